// Round 2
// baseline (1906.095 us; speedup 1.0000x reference)
//
#include <hip/hip_runtime.h>

typedef unsigned short u16;
typedef __attribute__((ext_vector_type(4))) float f32x4;
typedef __attribute__((ext_vector_type(8))) short short8;

#define B_ 64
#define L_ 196
#define D_ 512
#define T_ 31
#define V_ 32000

__device__ __forceinline__ float b2f(unsigned int u) {
    union { float f; unsigned int u; } x; x.u = u << 16; return x.f;
}
__device__ __forceinline__ u16 f2b(float f) {
    union { float f; unsigned int u; } x; x.f = f;
    unsigned int r = x.u + 0x7fffu + ((x.u >> 16) & 1u);
    return (u16)(r >> 16);
}
__device__ __forceinline__ void unpack8(uint4 v, float* f) {
    f[0] = b2f(v.x & 0xffffu); f[1] = b2f(v.x >> 16);
    f[2] = b2f(v.y & 0xffffu); f[3] = b2f(v.y >> 16);
    f[4] = b2f(v.z & 0xffffu); f[5] = b2f(v.z >> 16);
    f[6] = b2f(v.w & 0xffffu); f[7] = b2f(v.w >> 16);
}

// ------------- bulk f32 -> bf16 convert, 4 elems/thread ----------------------
__global__ __launch_bounds__(256) void convert_kernel(
        const float* __restrict__ src, u16* __restrict__ dst, int n4) {
    int i = blockIdx.x * 256 + threadIdx.x;
    if (i >= n4) return;
    float4 v = *(const float4*)(src + (size_t)i * 4);
    u16* d = dst + (size_t)i * 4;
    d[0] = f2b(v.x); d[1] = f2b(v.y); d[2] = f2b(v.z); d[3] = f2b(v.w);
}

// ------------- prep: WfT, Wcat = [W_ih[:,512:] ; W_hh], Wemb, emb gather -----
__global__ __launch_bounds__(256) void prep_kernel(
        const float* __restrict__ Wfeat, const float* __restrict__ Wih,
        const float* __restrict__ Whh, const float* __restrict__ table,
        const int* __restrict__ cap,
        u16* __restrict__ WfT, u16* __restrict__ Wcat,
        u16* __restrict__ Wemb, u16* __restrict__ Aemb) {
    int idx = blockIdx.x * 256 + threadIdx.x;
    if (idx < 512 * 512) {
        // WfT[e*512+d] = Wfeat[d*512+e]
        WfT[idx] = f2b(Wfeat[(idx & 511) * 512 + (idx >> 9)]);
    }
    if (idx < 2048 * 1024) {
        int j = idx >> 10, k = idx & 1023;
        Wcat[idx] = f2b((k < 512) ? Wih[j * 1024 + 512 + k] : Whh[j * 512 + (k - 512)]);
    }
    if (idx < 2048 * 512) {
        int j = idx >> 9, k = idx & 511;
        Wemb[idx] = f2b(Wih[j * 1024 + k]);
    }
    if (idx < 1984 * 512) {
        int m = idx >> 9, k = idx & 511;       // m = t*64 + b
        int t = m >> 6, b = m & 63;
        Aemb[idx] = f2b(table[(size_t)cap[b * 32 + t] * 512 + k]);
    }
}

// ------------- init: h0 = c0 = mean_l(img); hWh for step 0 -------------------
__global__ __launch_bounds__(512) void init_kernel(
        const float* __restrict__ img, const float* __restrict__ Wh,
        float* __restrict__ c, u16* __restrict__ xcat, float* __restrict__ hWh) {
    __shared__ float hl[512];
    int b = blockIdx.x, d = threadIdx.x;
    const float* p = img + (size_t)b * L_ * D_ + d;
    float s = 0.f;
    for (int l = 0; l < L_; l++) s += p[l * D_];
    float mean = s * (1.0f / 196.0f);
    c[b * 512 + d] = mean;
    xcat[b * 1024 + 512 + d] = f2b(mean);
    hl[d] = mean;
    __syncthreads();
    float acc = 0.f;
    const float* wp = Wh + d;                 // column d of W_h [D,D]
    for (int k = 0; k < 512; k++) acc += hl[k] * wp[k * 512];
    hWh[b * 512 + d] = acc;
}

// ------------- attention score: wave per (b,l), reduce over D=512 ------------
__global__ __launch_bounds__(256) void score_kernel(
        const u16* __restrict__ fp, const float* __restrict__ hWh,
        const float* __restrict__ att_bias, const float* __restrict__ v_att,
        float* __restrict__ score) {
    int b = blockIdx.y;
    int l = blockIdx.x * 4 + (threadIdx.x >> 6);
    int lane = threadIdx.x & 63;
    uint4 fv = *(const uint4*)(fp + ((size_t)(b * L_ + l)) * D_ + lane * 8);
    float4 h0 = *(const float4*)(hWh + b * D_ + lane * 8);
    float4 h1 = *(const float4*)(hWh + b * D_ + lane * 8 + 4);
    float4 v0 = *(const float4*)(v_att + lane * 8);
    float4 v1 = *(const float4*)(v_att + lane * 8 + 4);
    float ab = att_bias[l];
    float f[8];
    unpack8(fv, f);
    float hh[8] = {h0.x, h0.y, h0.z, h0.w, h1.x, h1.y, h1.z, h1.w};
    float vv[8] = {v0.x, v0.y, v0.z, v0.w, v1.x, v1.y, v1.z, v1.w};
    float acc = 0.f;
#pragma unroll
    for (int j = 0; j < 8; j++) {
        float a = f[j] + hh[j] + ab;
        a = fmaxf(a, 0.f);
        acc += a * vv[j];
    }
#pragma unroll
    for (int off = 32; off; off >>= 1) acc += __shfl_xor(acc, off, 64);
    if (lane == 0) score[b * L_ + l] = acc;
}

// ------------- softmax over L + context = alpha . img; block per b -----------
__global__ __launch_bounds__(256) void softctx_kernel(
        const float* __restrict__ score, const float* __restrict__ img,
        float* __restrict__ alphas_out, u16* __restrict__ xcat, int t) {
    __shared__ float sl[256];
    __shared__ float al[196];
    int b = blockIdx.x, tid = threadIdx.x;
    float s = (tid < L_) ? score[b * L_ + tid] : -3.4e38f;
    sl[tid] = s;
    __syncthreads();
    for (int off = 128; off; off >>= 1) {
        if (tid < off) sl[tid] = fmaxf(sl[tid], sl[tid + off]);
        __syncthreads();
    }
    float mx = sl[0];
    __syncthreads();
    float e = (tid < L_) ? expf(s - mx) : 0.f;
    sl[tid] = e;
    __syncthreads();
    for (int off = 128; off; off >>= 1) {
        if (tid < off) sl[tid] += sl[tid + off];
        __syncthreads();
    }
    float inv = 1.f / sl[0];
    if (tid < L_) {
        float a = e * inv;
        al[tid] = a;
        alphas_out[((size_t)(b * T_ + t)) * L_ + tid] = a;
    }
    __syncthreads();
    float c0 = 0.f, c1 = 0.f;
    const float* ib = img + (size_t)b * L_ * D_;
    for (int l = 0; l < L_; l++) {
        float a = al[l];
        c0 += a * ib[l * D_ + tid];
        c1 += a * ib[l * D_ + tid + 256];
    }
    xcat[b * 1024 + tid] = f2b(c0);
    xcat[b * 1024 + tid + 256] = f2b(c1);
}

// ------------- gates GEMM: [64 x 2048] = xcat[64x1024] @ Wcat^T, MFMA --------
// block tile 16m x 64n, 4 waves = 4 n-tiles; epilogue adds gates_emb + biases
__global__ __launch_bounds__(256) void gates_kernel(
        const u16* __restrict__ xcat, const u16* __restrict__ Wcat,
        const float* __restrict__ gemb, const float* __restrict__ bih,
        const float* __restrict__ bhh, float* __restrict__ gates, int t) {
    __shared__ __align__(16) u16 At[16 * 40];
    __shared__ __align__(16) u16 Bt[64 * 40];
    int tid = threadIdx.x, wave = tid >> 6, lane = tid & 63;
    int m0 = blockIdx.y * 16, n0 = blockIdx.x * 64;
    f32x4 acc = {0.f, 0.f, 0.f, 0.f};
    int sr = tid >> 2, sc = (tid & 3) * 8;
    const u16* Ap = xcat + (size_t)(m0 + (sr & 15)) * 1024 + sc;
    const u16* Bp = Wcat + (size_t)(n0 + sr) * 1024 + sc;
    int fm = lane & 15, fk = (lane >> 4) * 8;
    for (int k0 = 0; k0 < 1024; k0 += 32) {
        uint4 av = {0, 0, 0, 0};
        uint4 bv = *(const uint4*)(Bp + k0);
        if (tid < 64) av = *(const uint4*)(Ap + k0);
        __syncthreads();
        if (tid < 64) *(uint4*)(&At[(sr & 15) * 40 + sc]) = av;
        *(uint4*)(&Bt[sr * 40 + sc]) = bv;
        __syncthreads();
        short8 a = *(const short8*)(&At[fm * 40 + fk]);
        short8 bb = *(const short8*)(&Bt[(wave * 16 + fm) * 40 + fk]);
        acc = __builtin_amdgcn_mfma_f32_16x16x32_bf16(a, bb, acc, 0, 0, 0);
    }
    int crow = (lane >> 4) * 4, ccol = n0 + wave * 16 + (lane & 15);
#pragma unroll
    for (int r = 0; r < 4; r++) {
        int row = m0 + crow + r;   // batch index b
        float v = acc[r] + gemb[((size_t)(t * 64 + row)) * 2048 + ccol]
                + bih[ccol] + bhh[ccol];
        gates[row * 2048 + ccol] = v;
    }
}

// ------------- LSTM pointwise + h@W_h for NEXT step; block per b -------------
__global__ __launch_bounds__(512) void lstm_kernel(
        const float* __restrict__ gates, float* __restrict__ c,
        const float* __restrict__ Wh, u16* __restrict__ xcat,
        u16* __restrict__ hseq, float* __restrict__ hWh, int t) {
    __shared__ float hl[512];
    int b = blockIdx.x, d = threadIdx.x;
    const float* g = gates + b * 2048;
    float gi = g[d], gf = g[512 + d], gg = g[1024 + d], go = g[1536 + d];
    float cold = c[b * 512 + d];
    float si = 1.f / (1.f + expf(-gi));
    float sf = 1.f / (1.f + expf(-gf));
    float so = 1.f / (1.f + expf(-go));
    float cn = sf * cold + si * tanhf(gg);
    float hn = so * tanhf(cn);
    c[b * 512 + d] = cn;
    u16 hb = f2b(hn);
    xcat[b * 1024 + 512 + d] = hb;
    hseq[((size_t)(b * T_ + t)) * 512 + d] = hb;   // row m = b*31 + t
    hl[d] = hn;
    __syncthreads();
    float acc = 0.f;
    const float* wp = Wh + d;
    for (int k = 0; k < 512; k++) acc += hl[k] * wp[k * 512];
    hWh[b * 512 + d] = acc;
}

// ------------- generic MFMA GEMM: C[MxN] = A[MxK] @ B_T[NxK]^T ---------------
// 64x64 block tile, 4 waves 2x2, each wave 2x2 MFMA tiles of 16x16, BK=32
// MODE 0: C(bf16) = bf16(acc)   MODE 1: C(f32) = acc + bias[n]   MODE 2: C(f32) = acc
template <int MODE>
__global__ __launch_bounds__(256) void gemm64_kernel(
        const u16* __restrict__ A, const u16* __restrict__ Bm,
        int lda, int ldb, int K, void* __restrict__ Cv, int ldc,
        const float* __restrict__ bias) {
    __shared__ __align__(16) u16 At[64 * 40];
    __shared__ __align__(16) u16 Bt[64 * 40];
    int tid = threadIdx.x, wave = tid >> 6, lane = tid & 63;
    int wm = (wave >> 1) * 32, wn = (wave & 1) * 32;
    size_t m0 = (size_t)blockIdx.y * 64, n0 = (size_t)blockIdx.x * 64;
    f32x4 acc[2][2];
#pragma unroll
    for (int i = 0; i < 2; i++)
#pragma unroll
        for (int j = 0; j < 2; j++) acc[i][j] = {0.f, 0.f, 0.f, 0.f};
    int sr = tid >> 2, sc = (tid & 3) * 8;
    const u16* Ap = A + (m0 + sr) * (size_t)lda + sc;
    const u16* Bp = Bm + (n0 + sr) * (size_t)ldb + sc;
    int fm = lane & 15, fk = (lane >> 4) * 8;
    for (int k0 = 0; k0 < K; k0 += 32) {
        uint4 av = *(const uint4*)(Ap + k0);
        uint4 bv = *(const uint4*)(Bp + k0);
        __syncthreads();
        *(uint4*)(&At[sr * 40 + sc]) = av;
        *(uint4*)(&Bt[sr * 40 + sc]) = bv;
        __syncthreads();
        short8 a0 = *(const short8*)(&At[(wm + fm) * 40 + fk]);
        short8 a1 = *(const short8*)(&At[(wm + 16 + fm) * 40 + fk]);
        short8 b0 = *(const short8*)(&Bt[(wn + fm) * 40 + fk]);
        short8 b1 = *(const short8*)(&Bt[(wn + 16 + fm) * 40 + fk]);
        acc[0][0] = __builtin_amdgcn_mfma_f32_16x16x32_bf16(a0, b0, acc[0][0], 0, 0, 0);
        acc[0][1] = __builtin_amdgcn_mfma_f32_16x16x32_bf16(a0, b1, acc[0][1], 0, 0, 0);
        acc[1][0] = __builtin_amdgcn_mfma_f32_16x16x32_bf16(a1, b0, acc[1][0], 0, 0, 0);
        acc[1][1] = __builtin_amdgcn_mfma_f32_16x16x32_bf16(a1, b1, acc[1][1], 0, 0, 0);
    }
    int crow = (lane >> 4) * 4, ccol = lane & 15;
#pragma unroll
    for (int mi = 0; mi < 2; mi++)
#pragma unroll
        for (int ni = 0; ni < 2; ni++)
#pragma unroll
            for (int r = 0; r < 4; r++) {
                size_t row = m0 + wm + mi * 16 + crow + r;
                size_t col = n0 + wn + ni * 16 + ccol;
                float v = acc[mi][ni][r];
                if (MODE == 0) {
                    ((u16*)Cv)[row * (size_t)ldc + col] = f2b(v);
                } else {
                    if (MODE == 1) v += bias[col];
                    ((float*)Cv)[row * (size_t)ldc + col] = v;
                }
            }
}

extern "C" void kernel_launch(void* const* d_in, const int* in_sizes, int n_in,
                              void* d_out, int out_size, void* d_ws, size_t ws_size,
                              hipStream_t stream) {
    (void)in_sizes; (void)n_in; (void)out_size; (void)ws_size;
    const float* img   = (const float*)d_in[0];
    const int*   cap   = (const int*)d_in[1];
    const float* table = (const float*)d_in[2];
    const float* Wf    = (const float*)d_in[3];
    const float* Wh    = (const float*)d_in[4];
    const float* ab    = (const float*)d_in[5];
    const float* va    = (const float*)d_in[6];
    const float* Wih   = (const float*)d_in[7];
    const float* Whh   = (const float*)d_in[8];
    const float* bih   = (const float*)d_in[9];
    const float* bhh   = (const float*)d_in[10];
    const float* Wout  = (const float*)d_in[11];
    const float* bout  = (const float*)d_in[12];

    float* dout = (float*)d_out;                    // predictions [64,31,32000]
    float* alph = dout + (size_t)B_ * T_ * V_;      // alphas [64,31,196]

    char* w = (char*)d_ws;
    u16*   imgb  = (u16*)(w);                       // [12544,512] bf16
    u16*   fpb   = (u16*)(w + 12845056);            // [12544,512] bf16
    u16*   Woutb = (u16*)(w + 25690112);            // [32000,512] bf16
    u16*   Wcat  = (u16*)(w + 58458112);            // [2048,1024] bf16
    u16*   Wemb  = (u16*)(w + 62652416);            // [2048,512]  bf16
    u16*   WfT   = (u16*)(w + 64749568);            // [512,512]   bf16
    u16*   Aemb  = (u16*)(w + 65273856);            // [1984,512]  bf16
    u16*   hseq  = (u16*)(w + 67305472);            // [1984,512]  bf16
    float* gemb  = (float*)(w + 69337088);          // [1984,2048] f32
    u16*   xcat  = (u16*)(w + 85590016);            // [64,1024]   bf16
    float* gates = (float*)(w + 85721088);          // [64,2048]   f32
    float* score = (float*)(w + 86245376);          // [64,196]    f32
    float* hWh   = (float*)(w + 86295552);          // [64,512]    f32
    float* cbuf  = (float*)(w + 86426624);          // [64,512]    f32

    // upfront conversions / packing
    convert_kernel<<<6272, 256, 0, stream>>>(img, imgb, 12544 * 512 / 4);
    convert_kernel<<<16000, 256, 0, stream>>>(Wout, Woutb, 32000 * 512 / 4);
    prep_kernel<<<8192, 256, 0, stream>>>(Wf, Wih, Whh, table, cap, WfT, Wcat, Wemb, Aemb);
    // feat_proj = img @ W_feat : [12544,512] -> bf16
    gemm64_kernel<0><<<dim3(8, 196), 256, 0, stream>>>(imgb, WfT, 512, 512, 512, fpb, 512, nullptr);
    // gates_emb = emb @ W_ih[:, :512].T : [1984,2048] -> f32
    gemm64_kernel<2><<<dim3(32, 31), 256, 0, stream>>>(Aemb, Wemb, 512, 512, 512, gemb, 2048, nullptr);
    // h0 = c0 = mean; hWh for step 0
    init_kernel<<<64, 512, 0, stream>>>(img, Wh, cbuf, xcat, hWh);

    for (int t = 0; t < T_; t++) {
        score_kernel<<<dim3(49, 64), 256, 0, stream>>>(fpb, hWh, ab, va, score);
        softctx_kernel<<<64, 256, 0, stream>>>(score, img, alph, xcat, t);
        gates_kernel<<<dim3(32, 4), 256, 0, stream>>>(xcat, Wcat, gemb, bih, bhh, gates, t);
        lstm_kernel<<<64, 512, 0, stream>>>(gates, cbuf, Wh, xcat, hseq, hWh, t);
    }

    // predictions = hseq @ W_out.T + b_out : [1984,32000] -> f32
    gemm64_kernel<1><<<dim3(500, 31), 256, 0, stream>>>(hseq, Woutb, 512, 512, 512, dout, 32000, bout);
}